// Round 3
// baseline (1419.341 us; speedup 1.0000x reference)
//
#include <hip/hip_runtime.h>
#include <math.h>

// ---------------------------------------------------------------------------
// CapsNet forward on MI355X. All fp32 (threshold 4.4e-5 forbids bf16 inputs).
// conv2 (97.8 GFLOP) dominates: split-K implicit GEMM on the vector ALU.
// R3: force waves_per_eu(3,3) so RA gets 170 VGPRs -> acc+wr+xr resident.
//     (R2's VGPR_Count=84 proved the compiler was spilling/reloading: FMA
//      density only 60% of VALU-busy cycles.)
// ---------------------------------------------------------------------------

#define C1_BYTES   104857600u   // 256*256*400*4
#define PART_ELEMS 2359296      // 256*256*36
#define Y2_BYTES   9437184u
#define KSPLIT     6

// ============================ conv1: 9x9 s1 + ReLU ==========================
// grid 2048 = 256 b * 8 cgroups(32ch); block 320 = 20 oy * 16 ct (2 ch each)
__global__ __launch_bounds__(320) void conv1_k(
    const float* __restrict__ inp, const float* __restrict__ W1,
    const float* __restrict__ b1, float* __restrict__ out) {
  __shared__ __align__(16) float img[784];
  __shared__ float wl[81 * 34];          // [tap][32ch] pad->34
  const int blk = blockIdx.x;
  const int b = blk >> 3;
  const int cbase = (blk & 7) * 32;
  const int t = threadIdx.x;

  const float4* src = (const float4*)(inp + b * 784);
  for (int idx = t; idx < 196; idx += 320) ((float4*)img)[idx] = src[idx];
  for (int idx = t; idx < 2592; idx += 320) {
    int c = idx / 81, tap = idx - c * 81;
    wl[tap * 34 + c] = W1[(cbase + c) * 81 + tap];
  }
  __syncthreads();

  const int oy = t >> 4;                 // 0..19
  const int ct = t & 15;                 // 2 channels each
  const int c0 = cbase + ct * 2;
  const float bias0 = b1[c0], bias1 = b1[c0 + 1];
  float acc0[20], acc1[20];
#pragma unroll
  for (int ox = 0; ox < 20; ox++) { acc0[ox] = bias0; acc1[ox] = bias1; }

#pragma unroll 1
  for (int i = 0; i < 9; i++) {
    float wr0[9], wr1[9];
#pragma unroll
    for (int j = 0; j < 9; j++) {
      float2 wv = *(const float2*)&wl[(i * 9 + j) * 34 + ct * 2];
      wr0[j] = wv.x; wr1[j] = wv.y;
    }
    float xr[28];
    const float4* rp = (const float4*)&img[(oy + i) * 28];
#pragma unroll
    for (int k = 0; k < 7; k++) {
      float4 v = rp[k];
      xr[4 * k] = v.x; xr[4 * k + 1] = v.y; xr[4 * k + 2] = v.z; xr[4 * k + 3] = v.w;
    }
#pragma unroll
    for (int j = 0; j < 9; j++)
#pragma unroll
      for (int ox = 0; ox < 20; ox++) {
        acc0[ox] = fmaf(xr[ox + j], wr0[j], acc0[ox]);
        acc1[ox] = fmaf(xr[ox + j], wr1[j], acc1[ox]);
      }
  }
  float* o0 = out + (b * 256 + c0) * 400 + oy * 20;
#pragma unroll
  for (int k = 0; k < 5; k++)
    ((float4*)o0)[k] = make_float4(fmaxf(acc0[4*k],0.f), fmaxf(acc0[4*k+1],0.f),
                                   fmaxf(acc0[4*k+2],0.f), fmaxf(acc0[4*k+3],0.f));
  float* o1 = o0 + 400;
#pragma unroll
  for (int k = 0; k < 5; k++)
    ((float4*)o1)[k] = make_float4(fmaxf(acc1[4*k],0.f), fmaxf(acc1[4*k+1],0.f),
                                   fmaxf(acc1[4*k+2],0.f), fmaxf(acc1[4*k+3],0.f));
}

// =================== conv2: 9x9 s2 implicit GEMM, split-K ===================
// grid 768 = 32 bgroup(8b) * 4 octile(64oc) * 6 ksplit(43/42 ic); block 256
// thread = (bs 0..7, oct 0..15, oyh 0..1): 18 pos x 4 oc = 72 accumulators
// waves_per_eu(3,3): exactly 3 blocks/CU -> RA budget 170 VGPR, keep
// acc(72)+wr(36)+xr(20) register-resident (R2: VGPR=84 caused spill traffic).
__global__ __launch_bounds__(256)
__attribute__((amdgpu_waves_per_eu(3, 3)))
void conv2_k(
    const float* __restrict__ x, const float* __restrict__ W2,
    float* __restrict__ part) {
  __shared__ __align__(16) float xs[8 * 404];   // 8 images, pad 400->404
  __shared__ __align__(16) float ws[81 * 64];   // [tap][64oc] stride 64
  const int blk = blockIdx.x;
  const int bg = blk & 31;
  const int octile = (blk >> 5) & 3;
  const int ks = blk >> 7;                       // 0..5
  const int bbase = bg * 8, ocbase = octile * 64;
  const int icbase = (ks < 4) ? ks * 43 : 172 + (ks - 4) * 42;
  const int icn = (ks < 4) ? 43 : 42;
  const int t = threadIdx.x;
  const int bs = t & 7;
  const int oct = (t >> 3) & 15;
  const int oyh = t >> 7;                        // 0/1 -> rows 0-2 / 3-5
  const int yb2 = oyh * 6;                       // input-row offset (2*3*oyh)

  float acc[3][6][4];
#pragma unroll
  for (int a = 0; a < 3; a++)
#pragma unroll
    for (int o = 0; o < 6; o++)
#pragma unroll
      for (int c = 0; c < 4; c++) acc[a][o][c] = 0.f;

#pragma unroll 1
  for (int ici = 0; ici < icn; ici++) {
    const int ic = icbase + ici;
    __syncthreads();
    // stage x: 8 * 400 floats as float4 (coalesced, conflict-free)
    for (int idx = t; idx < 800; idx += 256) {
      int bs2 = idx / 100, w4 = idx - bs2 * 100;
      float4 v = ((const float4*)(x + ((bbase + bs2) * 256 + ic) * 400))[w4];
      *(float4*)&xs[bs2 * 404 + w4 * 4] = v;
    }
    // stage W2 slice oc-major: LDS writes lane-stride-1 (conflict-free);
    // global reads are per-lane contiguous streams within one oc (L1-backed)
    for (int idx = t; idx < 5184; idx += 256) {
      int tap = idx >> 6, oc = idx & 63;
      ws[tap * 64 + oc] = W2[(ocbase + oc) * 20736 + ic * 81 + tap];
    }
    __syncthreads();

    const float* xb = &xs[bs * 404 + yb2 * 20];
#pragma unroll 1
    for (int i = 0; i < 9; i++) {
      float4 wr[9];
#pragma unroll
      for (int j = 0; j < 9; j++) wr[j] = *(const float4*)&ws[(i * 9 + j) * 64 + oct * 4];
#pragma unroll
      for (int oyu = 0; oyu < 3; oyu++) {
        float xr[20];
        const float4* rp = (const float4*)&xb[(2 * oyu + i) * 20];
#pragma unroll
        for (int k = 0; k < 5; k++) {
          float4 v = rp[k];
          xr[4 * k] = v.x; xr[4 * k + 1] = v.y; xr[4 * k + 2] = v.z; xr[4 * k + 3] = v.w;
        }
#pragma unroll
        for (int j = 0; j < 9; j++)
#pragma unroll
          for (int ox = 0; ox < 6; ox++) {
            float xv = xr[2 * ox + j];
            acc[oyu][ox][0] = fmaf(xv, wr[j].x, acc[oyu][ox][0]);
            acc[oyu][ox][1] = fmaf(xv, wr[j].y, acc[oyu][ox][1]);
            acc[oyu][ox][2] = fmaf(xv, wr[j].z, acc[oyu][ox][2]);
            acc[oyu][ox][3] = fmaf(xv, wr[j].w, acc[oyu][ox][3]);
          }
      }
    }
  }
  // epilogue: partial[ks][b][oc][pos], thread owns pos [18*oyh, 18*oyh+18)
  const int bI = bbase + bs;
#pragma unroll
  for (int c = 0; c < 4; c++) {
    const int oc = ocbase + oct * 4 + c;
    float* p = part + ks * PART_ELEMS + (bI * 256 + oc) * 36 + oyh * 18;
#pragma unroll
    for (int oyu = 0; oyu < 3; oyu++)
#pragma unroll
      for (int ox2 = 0; ox2 < 3; ox2++)
        *(float2*)&p[oyu * 6 + ox2 * 2] =
            make_float2(acc[oyu][ox2 * 2][c], acc[oyu][ox2 * 2 + 1][c]);
  }
}

// ====================== reduce split-K partials + bias ======================
__global__ __launch_bounds__(256) void reduce_k(
    const float* __restrict__ part, const float* __restrict__ b2,
    float* __restrict__ y2) {
  const int i = blockIdx.x * 256 + threadIdx.x;  // < 2359296
  const int oc = (i / 36) & 255;
  float s = b2[oc];
#pragma unroll
  for (int ks = 0; ks < KSPLIT; ks++) s += part[ks * PART_ELEMS + i];
  y2[i] = s;
}

// ================= primary caps squash + predictions + routing ==============
// grid 8192 = g*256 + b; block 256
__global__ __launch_bounds__(256) void caps_k(
    const float* __restrict__ y2, const float* __restrict__ Wcaps,
    const float* __restrict__ b_route, float* __restrict__ vpart) {
  __shared__ float u[288];       // [36][8]
  __shared__ float usc[36];
  __shared__ float up[5760];     // [36][160]
  __shared__ float bl[360];      // [36][10]
  __shared__ float cl[360];
  __shared__ float sv[160];
  __shared__ float vv[160];
  __shared__ float scale[10];
  const int blk = blockIdx.x;
  const int g = blk >> 8, b = blk & 255;
  const int t = threadIdx.x;

  for (int idx = t; idx < 288; idx += 256) {
    int s = idx >> 3, d = idx & 7;
    u[idx] = y2[(b * 256 + g * 8 + d) * 36 + s];
  }
  for (int idx = t; idx < 360; idx += 256) bl[idx] = b_route[g * 360 + idx];
  __syncthreads();
  if (t < 36) {
    float l2 = 0.f;
#pragma unroll
    for (int d = 0; d < 8; d++) { float v = u[t * 8 + d]; l2 = fmaf(v, v, l2); }
    float l = sqrtf(l2);
    usc[t] = (l2 / (1.f + l2)) / (l + 1e-8f);
  }
  __syncthreads();
  for (int idx = t; idx < 288; idx += 256) u[idx] *= usc[idx >> 3];
  __syncthreads();
  // up[s][k] = sum_d u[s][d] * Wcaps[g][s][d][k]
  for (int idx = t; idx < 5760; idx += 256) {
    int s = idx / 160, k = idx - s * 160;
    const float* wp = Wcaps + (g * 36 + s) * 8 * 160 + k;
    float a = 0.f;
#pragma unroll
    for (int d = 0; d < 8; d++) a = fmaf(u[s * 8 + d], wp[d * 160], a);
    up[idx] = a;
  }
  __syncthreads();

  for (int r = 0; r < 3; r++) {
    if (t < 36) {
      float m = bl[t * 10];
#pragma unroll
      for (int oc = 1; oc < 10; oc++) m = fmaxf(m, bl[t * 10 + oc]);
      float e[10]; float sum = 0.f;
#pragma unroll
      for (int oc = 0; oc < 10; oc++) { e[oc] = expf(bl[t * 10 + oc] - m); sum += e[oc]; }
      float inv = 1.f / sum;
#pragma unroll
      for (int oc = 0; oc < 10; oc++) cl[t * 10 + oc] = e[oc] * inv;
    }
    __syncthreads();
    if (t < 160) {
      const int oc = t >> 4;
      float a = 0.f;
#pragma unroll 1
      for (int s = 0; s < 36; s++) a = fmaf(cl[s * 10 + oc], up[s * 160 + t], a);
      sv[t] = a;
    }
    __syncthreads();
    if (t < 10) {
      float l2 = 0.f;
#pragma unroll
      for (int od = 0; od < 16; od++) { float v = sv[t * 16 + od]; l2 = fmaf(v, v, l2); }
      scale[t] = (l2 / (1.f + l2)) / (sqrtf(l2) + 1e-8f);
    }
    __syncthreads();
    if (t < 160) vv[t] = sv[t] * scale[t >> 4];
    __syncthreads();
    if (r < 2) {
      for (int idx = t; idx < 360; idx += 256) {
        int s = idx / 10, oc = idx - s * 10;
        float a = 0.f;
#pragma unroll
        for (int od = 0; od < 16; od++)
          a = fmaf(up[s * 160 + oc * 16 + od], vv[oc * 16 + od], a);
        bl[idx] += a;
      }
      __syncthreads();
    }
  }
  if (t < 160) vpart[(b * 32 + g) * 160 + t] = vv[t];
}

// ================== final: sum over groups + probs ==========================
__global__ __launch_bounds__(192) void final_k(
    const float* __restrict__ vpart, float* __restrict__ out) {
  __shared__ float v[160];
  const int b = blockIdx.x, t = threadIdx.x;
  if (t < 160) {
    float a = 0.f;
#pragma unroll 1
    for (int g = 0; g < 32; g++) a += vpart[(b * 32 + g) * 160 + t];
    v[t] = a;
    out[b * 160 + t] = a;
  }
  __syncthreads();
  if (t < 10) {
    float l2 = 0.f;
#pragma unroll
    for (int od = 0; od < 16; od++) { float x = v[t * 16 + od]; l2 = fmaf(x, x, l2); }
    out[40960 + b * 10 + t] = sqrtf(l2);
  }
}

// ===========================================================================
extern "C" void kernel_launch(void* const* d_in, const int* in_sizes, int n_in,
                              void* d_out, int out_size, void* d_ws, size_t ws_size,
                              hipStream_t stream) {
  const float* inp     = (const float*)d_in[0];
  const float* W1      = (const float*)d_in[1];
  const float* b1      = (const float*)d_in[2];
  const float* W2      = (const float*)d_in[3];
  const float* b2      = (const float*)d_in[4];
  const float* Wcaps   = (const float*)d_in[5];
  const float* b_route = (const float*)d_in[6];
  float* out = (float*)d_out;
  char* ws = (char*)d_ws;

  float* conv1out = (float*)(ws);                    // 104.9 MB, dead after conv2
  float* part     = (float*)(ws + C1_BYTES);         // 56.6 MB (6 chunks)
  float* y2       = (float*)(ws);                    // aliases dead conv1out
  float* vpart    = (float*)(ws + Y2_BYTES);         // aliases dead conv1out

  conv1_k <<<2048, 320, 0, stream>>>(inp, W1, b1, conv1out);
  conv2_k <<<768, 256, 0, stream>>>(conv1out, W2, part);
  reduce_k<<<9216, 256, 0, stream>>>(part, b2, y2);
  caps_k  <<<8192, 256, 0, stream>>>(y2, Wcaps, b_route, vpart);
  final_k <<<256, 192, 0, stream>>>(vpart, out);
}

// Round 4
// 1014.939 us; speedup vs baseline: 1.3984x; 1.3984x over previous
//
#include <hip/hip_runtime.h>
#include <math.h>

// ---------------------------------------------------------------------------
// CapsNet forward on MI355X.
// R4: conv2 via MFMA bf16 double-split (x=hi+lo, w=hi+lo, 3 mfma terms;
//     lo*lo dropped ~2^-16 rel << 4.4e-5 threshold). GEMM M=9216,N=256,
//     K=84taps*ic. 512 blocks = 64 Mblocks x 8 ic-splits (ks=blk&7 -> XCD-
//     pinned weight slice in L2). A from parity-split LDS x-slab (conflict-
//     free 16B frags), B staged per K-step. atomicAdd fp32 epilogue into y2.
// ---------------------------------------------------------------------------

typedef float floatx4 __attribute__((ext_vector_type(4)));
typedef __bf16 bf16x8 __attribute__((ext_vector_type(8)));

#define XHI_OFF 0u
#define XLO_OFF 52428800u
#define WHI_OFF 104857600u
#define WLO_OFF 115474432u
#define Y2_OFF  126091264u
#define VP_OFF  135528448u
#define Y2_BYTES 9437184u

__device__ __forceinline__ void bf16split(float v, short& hs, short& ls) {
  unsigned u = __builtin_bit_cast(unsigned, v);
  unsigned r = (u + 0x7FFFu + ((u >> 16) & 1u)) & 0xFFFF0000u;
  hs = (short)(r >> 16);
  float lo = v - __builtin_bit_cast(float, r);
  unsigned u2 = __builtin_bit_cast(unsigned, lo);
  unsigned r2 = u2 + 0x7FFFu + ((u2 >> 16) & 1u);
  ls = (short)(r2 >> 16);
}

// ============================ conv1: 9x9 s1 + ReLU ==========================
// grid 2048 = 256 b * 8 cgroups(32ch); block 320 = 20 oy * 16 ct (2 ch each)
// Emits x_hi/x_lo bf16 in [b][pos(400)][ic(256)] layout (GEMM-A friendly).
__global__ __launch_bounds__(320) void conv1_k(
    const float* __restrict__ inp, const float* __restrict__ W1,
    const float* __restrict__ b1, short* __restrict__ xhi,
    short* __restrict__ xlo) {
  __shared__ __align__(16) float img[784];
  __shared__ float wl[81 * 34];
  const int blk = blockIdx.x;
  const int b = blk >> 3;
  const int cbase = (blk & 7) * 32;
  const int t = threadIdx.x;

  const float4* src = (const float4*)(inp + b * 784);
  for (int idx = t; idx < 196; idx += 320) ((float4*)img)[idx] = src[idx];
  for (int idx = t; idx < 2592; idx += 320) {
    int c = idx / 81, tap = idx - c * 81;
    wl[tap * 34 + c] = W1[(cbase + c) * 81 + tap];
  }
  __syncthreads();

  const int oy = t >> 4;
  const int ct = t & 15;
  const int c0 = cbase + ct * 2;
  const float bias0 = b1[c0], bias1 = b1[c0 + 1];
  float acc0[20], acc1[20];
#pragma unroll
  for (int ox = 0; ox < 20; ox++) { acc0[ox] = bias0; acc1[ox] = bias1; }

#pragma unroll 1
  for (int i = 0; i < 9; i++) {
    float wr0[9], wr1[9];
#pragma unroll
    for (int j = 0; j < 9; j++) {
      float2 wv = *(const float2*)&wl[(i * 9 + j) * 34 + ct * 2];
      wr0[j] = wv.x; wr1[j] = wv.y;
    }
    float xr[28];
    const float4* rp = (const float4*)&img[(oy + i) * 28];
#pragma unroll
    for (int k = 0; k < 7; k++) {
      float4 v = rp[k];
      xr[4 * k] = v.x; xr[4 * k + 1] = v.y; xr[4 * k + 2] = v.z; xr[4 * k + 3] = v.w;
    }
#pragma unroll
    for (int j = 0; j < 9; j++)
#pragma unroll
      for (int ox = 0; ox < 20; ox++) {
        acc0[ox] = fmaf(xr[ox + j], wr0[j], acc0[ox]);
        acc1[ox] = fmaf(xr[ox + j], wr1[j], acc1[ox]);
      }
  }
  const long pbase = (long)(b * 400 + oy * 20) * 256 + c0;
#pragma unroll
  for (int ox = 0; ox < 20; ox++) {
    float v0 = fmaxf(acc0[ox], 0.f), v1 = fmaxf(acc1[ox], 0.f);
    short h0, l0, h1, l1;
    bf16split(v0, h0, l0);
    bf16split(v1, h1, l1);
    long a = pbase + (long)ox * 256;
    *(short2*)&xhi[a] = make_short2(h0, h1);
    *(short2*)&xlo[a] = make_short2(l0, l1);
  }
}

// ================= W2 transform: fp32 [oc][ic][81] -> bf16 hi/lo ============
// out layout: [tap(81)][icg(32)][oc(256)][ics(8)]  (ic = icg*8+ics)
__global__ __launch_bounds__(256) void wtrans_k(
    const float* __restrict__ W2, short* __restrict__ whi,
    short* __restrict__ wlo) {
  const int idx = blockIdx.x * 256 + threadIdx.x;  // < 5308416
  const int ics = idx & 7;
  const int oc = (idx >> 3) & 255;
  const int icg = (idx >> 11) & 31;
  const int tap = idx >> 16;
  const int ic = icg * 8 + ics;
  float v = W2[(oc * 256 + ic) * 81 + tap];
  short h, l;
  bf16split(v, h, l);
  whi[idx] = h;
  wlo[idx] = l;
}

// ================= conv2: MFMA bf16-split implicit GEMM =====================
// grid 512: ks = blk&7 (ic-split of 32, XCD-pinned), mb = blk>>3 (4 images).
// Block M144(9 m-tiles) x N256; 4 waves each 9m x 4n tiles (N64/wave).
// K-step = 32 = 4 taps x 8 ic (quad q -> tap, elem e -> ic). 84 taps (3 pad).
__global__ __launch_bounds__(256) void conv2_k(
    const short* __restrict__ xhi, const short* __restrict__ xlo,
    const short* __restrict__ whi, const short* __restrict__ wlo,
    float* __restrict__ y2) {
  // slab: [parity(2)][img(4)][iy(20)][ixh(10)][ic(8)] shorts = 12800
  __shared__ __align__(16) short slabA[12800];   // 25.6 KB (one precision)
  __shared__ __align__(16) short Bh[8192];       // [tap(4)][oc(256)][ic(8)] 16 KB
  __shared__ __align__(16) short Bl[8192];       // 16 KB

  const int blk = blockIdx.x;
  const int ks = blk & 7;
  const int mb = blk >> 3;
  const int b0 = mb * 4;
  const int t = threadIdx.x;
  const int lane = t & 63;
  const int q = lane >> 4;
  const int ln16 = lane & 15;
  const int wv = t >> 6;

  // per-lane m geometry for the 9 m-tiles
  int combo[9];
#pragma unroll
  for (int mt = 0; mt < 9; mt++) {
    int row = mt * 16 + ln16;        // 0..143
    int im = row / 36;
    int pos = row - im * 36;
    int oy = pos / 6, ox = pos - oy * 6;
    combo[mt] = im * 1600 + oy * 160 + ox * 8;   // shorts, within a parity plane
  }

  floatx4 acc[9][4];
#pragma unroll
  for (int mt = 0; mt < 9; mt++)
#pragma unroll
    for (int nt = 0; nt < 4; nt++) acc[mt][nt] = (floatx4)0.f;

#pragma unroll 1
  for (int icg = 0; icg < 4; icg++) {
    const int icgG = ks * 4 + icg;           // global 8-ic group
    const long icoff = (long)icgG * 8;

    // ---------------- HI phase: A_hi * (B_hi + B_lo) ----------------
    __syncthreads();
    for (int idx = t; idx < 1600; idx += 256) {   // stage x_hi slab
      int im = idx / 400, p = idx - im * 400;
      int iy = p / 20, ix = p - iy * 20;
      int dst = (ix & 1) * 6400 + im * 1600 + iy * 80 + (ix >> 1) * 8;
      *(uint4*)&slabA[dst] =
          *(const uint4*)&xhi[((long)(b0 + im) * 400 + p) * 256 + icoff];
    }
    __syncthreads();

#pragma unroll 1
    for (int kst = 0; kst < 21; kst++) {
      const int t0 = kst * 4;
      __syncthreads();
      for (int idx = t; idx < 1024; idx += 256) {   // stage B hi+lo
        int tp = idx >> 8, oc = idx & 255;
        int tg = t0 + tp;
        uint4 vh = make_uint4(0, 0, 0, 0), vl = make_uint4(0, 0, 0, 0);
        if (tg < 81) {
          long s = (((long)tg * 32 + icgG) * 256 + oc) * 8;
          vh = *(const uint4*)&whi[s];
          vl = *(const uint4*)&wlo[s];
        }
        *(uint4*)&Bh[(tp * 256 + oc) * 8] = vh;
        *(uint4*)&Bl[(tp * 256 + oc) * 8] = vl;
      }
      __syncthreads();

      const int tap = t0 + q;
      const int i = tap / 9, j = tap - i * 9;
      const int aoff = (j & 1) * 6400 + i * 80 + (j >> 1) * 8;
      bf16x8 bh[4], bl[4];
#pragma unroll
      for (int nt = 0; nt < 4; nt++) {
        int oc = wv * 64 + nt * 16 + ln16;
        bh[nt] = *(const bf16x8*)&Bh[(q * 256 + oc) * 8];
        bl[nt] = *(const bf16x8*)&Bl[(q * 256 + oc) * 8];
      }
#pragma unroll
      for (int mt = 0; mt < 9; mt++) {
        bf16x8 a = *(const bf16x8*)&slabA[aoff + combo[mt]];
#pragma unroll
        for (int nt = 0; nt < 4; nt++) {
          acc[mt][nt] = __builtin_amdgcn_mfma_f32_16x16x32_bf16(a, bh[nt], acc[mt][nt], 0, 0, 0);
          acc[mt][nt] = __builtin_amdgcn_mfma_f32_16x16x32_bf16(a, bl[nt], acc[mt][nt], 0, 0, 0);
        }
      }
    }

    // ---------------- LO phase: A_lo * B_hi ----------------
    __syncthreads();
    for (int idx = t; idx < 1600; idx += 256) {   // stage x_lo slab
      int im = idx / 400, p = idx - im * 400;
      int iy = p / 20, ix = p - iy * 20;
      int dst = (ix & 1) * 6400 + im * 1600 + iy * 80 + (ix >> 1) * 8;
      *(uint4*)&slabA[dst] =
          *(const uint4*)&xlo[((long)(b0 + im) * 400 + p) * 256 + icoff];
    }
    __syncthreads();

#pragma unroll 1
    for (int kst = 0; kst < 21; kst++) {
      const int t0 = kst * 4;
      __syncthreads();
      for (int idx = t; idx < 1024; idx += 256) {   // stage B hi
        int tp = idx >> 8, oc = idx & 255;
        int tg = t0 + tp;
        uint4 vh = make_uint4(0, 0, 0, 0);
        if (tg < 81)
          vh = *(const uint4*)&whi[(((long)tg * 32 + icgG) * 256 + oc) * 8];
        *(uint4*)&Bh[(tp * 256 + oc) * 8] = vh;
      }
      __syncthreads();

      const int tap = t0 + q;
      const int i = tap / 9, j = tap - i * 9;
      const int aoff = (j & 1) * 6400 + i * 80 + (j >> 1) * 8;
      bf16x8 bh[4];
#pragma unroll
      for (int nt = 0; nt < 4; nt++) {
        int oc = wv * 64 + nt * 16 + ln16;
        bh[nt] = *(const bf16x8*)&Bh[(q * 256 + oc) * 8];
      }
#pragma unroll
      for (int mt = 0; mt < 9; mt++) {
        bf16x8 a = *(const bf16x8*)&slabA[aoff + combo[mt]];
#pragma unroll
        for (int nt = 0; nt < 4; nt++)
          acc[mt][nt] = __builtin_amdgcn_mfma_f32_16x16x32_bf16(a, bh[nt], acc[mt][nt], 0, 0, 0);
      }
    }
  }

  // epilogue: C/D layout col(n)=lane&15, row(m)=q*4+r; atomic over 8 ic-splits
#pragma unroll
  for (int mt = 0; mt < 9; mt++)
#pragma unroll
    for (int nt = 0; nt < 4; nt++) {
      int oc = wv * 64 + nt * 16 + ln16;
      int rowb = mb * 144 + mt * 16 + q * 4;
#pragma unroll
      for (int r = 0; r < 4; r++)
        atomicAdd(&y2[(long)(rowb + r) * 256 + oc], acc[mt][nt][r]);
    }
}

// ================= primary caps squash + predictions + routing ==============
// grid 8192 = g*256 + b; block 256.  y2 layout: [b][pos(36)][c(256)], pre-bias.
__global__ __launch_bounds__(256) void caps_k(
    const float* __restrict__ y2, const float* __restrict__ b2,
    const float* __restrict__ Wcaps, const float* __restrict__ b_route,
    float* __restrict__ vpart) {
  __shared__ float u[288];
  __shared__ float usc[36];
  __shared__ float up[5760];
  __shared__ float bl[360];
  __shared__ float cl[360];
  __shared__ float sv[160];
  __shared__ float vv[160];
  __shared__ float scale[10];
  const int blk = blockIdx.x;
  const int g = blk >> 8, b = blk & 255;
  const int t = threadIdx.x;

  for (int idx = t; idx < 288; idx += 256) {
    int s = idx >> 3, d = idx & 7;
    u[idx] = y2[((long)b * 36 + s) * 256 + g * 8 + d] + b2[g * 8 + d];
  }
  for (int idx = t; idx < 360; idx += 256) bl[idx] = b_route[g * 360 + idx];
  __syncthreads();
  if (t < 36) {
    float l2 = 0.f;
#pragma unroll
    for (int d = 0; d < 8; d++) { float v = u[t * 8 + d]; l2 = fmaf(v, v, l2); }
    float l = sqrtf(l2);
    usc[t] = (l2 / (1.f + l2)) / (l + 1e-8f);
  }
  __syncthreads();
  for (int idx = t; idx < 288; idx += 256) u[idx] *= usc[idx >> 3];
  __syncthreads();
  for (int idx = t; idx < 5760; idx += 256) {
    int s = idx / 160, k = idx - s * 160;
    const float* wp = Wcaps + (g * 36 + s) * 8 * 160 + k;
    float a = 0.f;
#pragma unroll
    for (int d = 0; d < 8; d++) a = fmaf(u[s * 8 + d], wp[d * 160], a);
    up[idx] = a;
  }
  __syncthreads();

  for (int r = 0; r < 3; r++) {
    if (t < 36) {
      float m = bl[t * 10];
#pragma unroll
      for (int oc = 1; oc < 10; oc++) m = fmaxf(m, bl[t * 10 + oc]);
      float e[10]; float sum = 0.f;
#pragma unroll
      for (int oc = 0; oc < 10; oc++) { e[oc] = expf(bl[t * 10 + oc] - m); sum += e[oc]; }
      float inv = 1.f / sum;
#pragma unroll
      for (int oc = 0; oc < 10; oc++) cl[t * 10 + oc] = e[oc] * inv;
    }
    __syncthreads();
    if (t < 160) {
      const int oc = t >> 4;
      float a = 0.f;
#pragma unroll 1
      for (int s = 0; s < 36; s++) a = fmaf(cl[s * 10 + oc], up[s * 160 + t], a);
      sv[t] = a;
    }
    __syncthreads();
    if (t < 10) {
      float l2 = 0.f;
#pragma unroll
      for (int od = 0; od < 16; od++) { float v = sv[t * 16 + od]; l2 = fmaf(v, v, l2); }
      scale[t] = (l2 / (1.f + l2)) / (sqrtf(l2) + 1e-8f);
    }
    __syncthreads();
    if (t < 160) vv[t] = sv[t] * scale[t >> 4];
    __syncthreads();
    if (r < 2) {
      for (int idx = t; idx < 360; idx += 256) {
        int s = idx / 10, oc = idx - s * 10;
        float a = 0.f;
#pragma unroll
        for (int od = 0; od < 16; od++)
          a = fmaf(up[s * 160 + oc * 16 + od], vv[oc * 16 + od], a);
        bl[idx] += a;
      }
      __syncthreads();
    }
  }
  if (t < 160) vpart[(b * 32 + g) * 160 + t] = vv[t];
}

// ================== final: sum over groups + probs ==========================
__global__ __launch_bounds__(192) void final_k(
    const float* __restrict__ vpart, float* __restrict__ out) {
  __shared__ float v[160];
  const int b = blockIdx.x, t = threadIdx.x;
  if (t < 160) {
    float a = 0.f;
#pragma unroll 1
    for (int g = 0; g < 32; g++) a += vpart[(b * 32 + g) * 160 + t];
    v[t] = a;
    out[b * 160 + t] = a;
  }
  __syncthreads();
  if (t < 10) {
    float l2 = 0.f;
#pragma unroll
    for (int od = 0; od < 16; od++) { float x = v[t * 16 + od]; l2 = fmaf(x, x, l2); }
    out[40960 + b * 10 + t] = sqrtf(l2);
  }
}

// ===========================================================================
extern "C" void kernel_launch(void* const* d_in, const int* in_sizes, int n_in,
                              void* d_out, int out_size, void* d_ws, size_t ws_size,
                              hipStream_t stream) {
  const float* inp     = (const float*)d_in[0];
  const float* W1      = (const float*)d_in[1];
  const float* b1      = (const float*)d_in[2];
  const float* W2      = (const float*)d_in[3];
  const float* b2      = (const float*)d_in[4];
  const float* Wcaps   = (const float*)d_in[5];
  const float* b_route = (const float*)d_in[6];
  float* out = (float*)d_out;
  char* ws = (char*)d_ws;

  short* xhi = (short*)(ws + XHI_OFF);
  short* xlo = (short*)(ws + XLO_OFF);
  short* whi = (short*)(ws + WHI_OFF);
  short* wlo = (short*)(ws + WLO_OFF);
  float* y2  = (float*)(ws + Y2_OFF);
  float* vp  = (float*)(ws + VP_OFF);

  hipMemsetAsync(y2, 0, Y2_BYTES, stream);
  conv1_k <<<2048, 320, 0, stream>>>(inp, W1, b1, xhi, xlo);
  wtrans_k<<<20736, 256, 0, stream>>>(W2, whi, wlo);
  conv2_k <<<512, 256, 0, stream>>>(xhi, xlo, whi, wlo, y2);
  caps_k  <<<8192, 256, 0, stream>>>(y2, b2, Wcaps, b_route, vp);
  final_k <<<256, 192, 0, stream>>>(vp, out);
}

// Round 5
// 588.059 us; speedup vs baseline: 2.4136x; 1.7259x over previous
//
#include <hip/hip_runtime.h>
#include <math.h>

// ---------------------------------------------------------------------------
// CapsNet forward on MI355X.
// R5: conv2 MFMA bf16 double-split, B fragments loaded DIRECTLY global->reg
//     (16B/lane, frag-ready layout, XCD-L2-resident slice) with 1-step
//     register prefetch. No B LDS, no per-kst barriers (R4 was barrier-bound:
//     MfmaUtil 16%, VALUBusy 11%). LDS holds only the A slab (25.6 KB).
//     W buffers padded to 84 taps (zero-filled) -> no tap predication.
// ---------------------------------------------------------------------------

typedef float floatx4 __attribute__((ext_vector_type(4)));
typedef __bf16 bf16x8 __attribute__((ext_vector_type(8)));

#define XHI_OFF 0u
#define XLO_OFF 52428800u
#define WHI_OFF 104857600u          // 84*32*256*8 shorts = 11010048 B
#define WLO_OFF 115867648u
#define Y2_OFF  126877696u
#define VP_OFF  136314880u
#define Y2_BYTES 9437184u

__device__ __forceinline__ void bf16split(float v, short& hs, short& ls) {
  unsigned u = __builtin_bit_cast(unsigned, v);
  unsigned r = (u + 0x7FFFu + ((u >> 16) & 1u)) & 0xFFFF0000u;
  hs = (short)(r >> 16);
  float lo = v - __builtin_bit_cast(float, r);
  unsigned u2 = __builtin_bit_cast(unsigned, lo);
  unsigned r2 = u2 + 0x7FFFu + ((u2 >> 16) & 1u);
  ls = (short)(r2 >> 16);
}

// ============================ conv1: 9x9 s1 + ReLU ==========================
// Emits x_hi/x_lo bf16 in [b][pos(400)][ic(256)] layout (GEMM-A friendly).
__global__ __launch_bounds__(320) void conv1_k(
    const float* __restrict__ inp, const float* __restrict__ W1,
    const float* __restrict__ b1, short* __restrict__ xhi,
    short* __restrict__ xlo) {
  __shared__ __align__(16) float img[784];
  __shared__ float wl[81 * 34];
  const int blk = blockIdx.x;
  const int b = blk >> 3;
  const int cbase = (blk & 7) * 32;
  const int t = threadIdx.x;

  const float4* src = (const float4*)(inp + b * 784);
  for (int idx = t; idx < 196; idx += 320) ((float4*)img)[idx] = src[idx];
  for (int idx = t; idx < 2592; idx += 320) {
    int c = idx / 81, tap = idx - c * 81;
    wl[tap * 34 + c] = W1[(cbase + c) * 81 + tap];
  }
  __syncthreads();

  const int oy = t >> 4;
  const int ct = t & 15;
  const int c0 = cbase + ct * 2;
  const float bias0 = b1[c0], bias1 = b1[c0 + 1];
  float acc0[20], acc1[20];
#pragma unroll
  for (int ox = 0; ox < 20; ox++) { acc0[ox] = bias0; acc1[ox] = bias1; }

#pragma unroll 1
  for (int i = 0; i < 9; i++) {
    float wr0[9], wr1[9];
#pragma unroll
    for (int j = 0; j < 9; j++) {
      float2 wv = *(const float2*)&wl[(i * 9 + j) * 34 + ct * 2];
      wr0[j] = wv.x; wr1[j] = wv.y;
    }
    float xr[28];
    const float4* rp = (const float4*)&img[(oy + i) * 28];
#pragma unroll
    for (int k = 0; k < 7; k++) {
      float4 v = rp[k];
      xr[4 * k] = v.x; xr[4 * k + 1] = v.y; xr[4 * k + 2] = v.z; xr[4 * k + 3] = v.w;
    }
#pragma unroll
    for (int j = 0; j < 9; j++)
#pragma unroll
      for (int ox = 0; ox < 20; ox++) {
        acc0[ox] = fmaf(xr[ox + j], wr0[j], acc0[ox]);
        acc1[ox] = fmaf(xr[ox + j], wr1[j], acc1[ox]);
      }
  }
  const long pbase = (long)(b * 400 + oy * 20) * 256 + c0;
#pragma unroll
  for (int ox = 0; ox < 20; ox++) {
    float v0 = fmaxf(acc0[ox], 0.f), v1 = fmaxf(acc1[ox], 0.f);
    short h0, l0, h1, l1;
    bf16split(v0, h0, l0);
    bf16split(v1, h1, l1);
    long a = pbase + (long)ox * 256;
    *(short2*)&xhi[a] = make_short2(h0, h1);
    *(short2*)&xlo[a] = make_short2(l0, l1);
  }
}

// ======= W2 transform: fp32 [oc][ic][81] -> bf16 hi/lo, 84-tap padded =======
// out layout: [tap(84)][icg(32)][oc(256)][ics(8)]; taps 81..83 zero.
__global__ __launch_bounds__(256) void wtrans_k(
    const float* __restrict__ W2, short* __restrict__ whi,
    short* __restrict__ wlo) {
  const int idx = blockIdx.x * 256 + threadIdx.x;  // < 5505024
  const int ics = idx & 7;
  const int oc = (idx >> 3) & 255;
  const int icg = (idx >> 11) & 31;
  const int tap = idx >> 16;
  short h = 0, l = 0;
  if (tap < 81) {
    const int ic = icg * 8 + ics;
    bf16split(W2[(oc * 256 + ic) * 81 + tap], h, l);
  }
  whi[idx] = h;
  wlo[idx] = l;
}

// ================= conv2: MFMA bf16-split implicit GEMM =====================
// grid 512: ks = blk&7 (ic-split, XCD-pinned L2 slice), mb = blk>>3 (4 imgs).
// Block M144(9 m-tiles) x N256; 4 waves, each 9m x 4n (N64/wave).
// K-step 32 = 4 taps(quad) x 8 ic(elem). B frags: direct global->reg with
// 1-step prefetch; A frags from parity-split LDS slab. 84 taps (3 zero-pad).
__global__ __launch_bounds__(256, 2) void conv2_k(
    const short* __restrict__ xhi, const short* __restrict__ xlo,
    const short* __restrict__ whi, const short* __restrict__ wlo,
    float* __restrict__ y2) {
  // slab: [parity(2)][img(4)][iy(20)][ixh(10)][ic(8)] shorts = 12800 (25.6KB)
  __shared__ __align__(16) short slabA[12800];

  const int blk = blockIdx.x;
  const int ks = blk & 7;
  const int mb = blk >> 3;
  const int b0 = mb * 4;
  const int t = threadIdx.x;
  const int lane = t & 63;
  const int q = lane >> 4;
  const int ln16 = lane & 15;
  const int wv = t >> 6;

  int combo[9];
#pragma unroll
  for (int mt = 0; mt < 9; mt++) {
    int row = mt * 16 + ln16;
    int im = row / 36;
    int pos = row - im * 36;
    int oy = pos / 6, ox = pos - oy * 6;
    combo[mt] = im * 1600 + oy * 160 + ox * 8;
  }

  floatx4 acc[9][4];
#pragma unroll
  for (int mt = 0; mt < 9; mt++)
#pragma unroll
    for (int nt = 0; nt < 4; nt++) acc[mt][nt] = (floatx4)0.f;

#pragma unroll 1
  for (int icg = 0; icg < 4; icg++) {
    const int icgG = ks * 4 + icg;
    const long icoff = (long)icgG * 8;
    // per-lane weight base (shorts): ((tap*32 + icgG)*256 + oc)*8
    const long wb0 = ((long)icgG * 256 + wv * 64 + ln16) * 8 + (long)q * 65536;

    // ---------------- HI phase: A_hi * (B_hi + B_lo) ----------------
    __syncthreads();
    for (int idx = t; idx < 1600; idx += 256) {
      int im = idx / 400, p = idx - im * 400;
      int iy = p / 20, ix = p - iy * 20;
      int dst = (ix & 1) * 6400 + im * 1600 + iy * 80 + (ix >> 1) * 8;
      *(uint4*)&slabA[dst] =
          *(const uint4*)&xhi[((long)(b0 + im) * 400 + p) * 256 + icoff];
    }
    __syncthreads();

    {
      bf16x8 cbh[4], cbl[4];
#pragma unroll
      for (int nt = 0; nt < 4; nt++) {
        long a = wb0 + nt * 128;              // t0 = 0
        cbh[nt] = *(const bf16x8*)&whi[a];
        cbl[nt] = *(const bf16x8*)&wlo[a];
      }
#pragma unroll 1
      for (int kst = 0; kst < 21; kst++) {
        // prefetch next k-step's B frags (clamped; tap 80..83 are zero-pad)
        const int t0n = (kst < 20) ? (kst + 1) * 4 : 80;
        bf16x8 nbh[4], nbl[4];
#pragma unroll
        for (int nt = 0; nt < 4; nt++) {
          long a = wb0 + (long)t0n * 262144 + nt * 128;  // 4tap*65536... t0n*4? no:
          // NOTE: wb0 already includes q*65536; per-kst advance = 4 taps = 4*65536
          a = wb0 + (long)t0n * 65536 + nt * 128;
          nbh[nt] = *(const bf16x8*)&whi[a];
          nbl[nt] = *(const bf16x8*)&wlo[a];
        }
        const int tap = kst * 4 + q;
        const int i = tap / 9, j = tap - i * 9;
        const int aoff = (j & 1) * 6400 + i * 80 + (j >> 1) * 8;
#pragma unroll
        for (int mt = 0; mt < 9; mt++) {
          bf16x8 a = *(const bf16x8*)&slabA[aoff + combo[mt]];
#pragma unroll
          for (int nt = 0; nt < 4; nt++) {
            acc[mt][nt] = __builtin_amdgcn_mfma_f32_16x16x32_bf16(a, cbh[nt], acc[mt][nt], 0, 0, 0);
            acc[mt][nt] = __builtin_amdgcn_mfma_f32_16x16x32_bf16(a, cbl[nt], acc[mt][nt], 0, 0, 0);
          }
        }
#pragma unroll
        for (int nt = 0; nt < 4; nt++) { cbh[nt] = nbh[nt]; cbl[nt] = nbl[nt]; }
      }
    }

    // ---------------- LO phase: A_lo * B_hi ----------------
    __syncthreads();
    for (int idx = t; idx < 1600; idx += 256) {
      int im = idx / 400, p = idx - im * 400;
      int iy = p / 20, ix = p - iy * 20;
      int dst = (ix & 1) * 6400 + im * 1600 + iy * 80 + (ix >> 1) * 8;
      *(uint4*)&slabA[dst] =
          *(const uint4*)&xlo[((long)(b0 + im) * 400 + p) * 256 + icoff];
    }
    __syncthreads();

    {
      bf16x8 cbh[4];
#pragma unroll
      for (int nt = 0; nt < 4; nt++) cbh[nt] = *(const bf16x8*)&whi[wb0 + nt * 128];
#pragma unroll 1
      for (int kst = 0; kst < 21; kst++) {
        const int t0n = (kst < 20) ? (kst + 1) * 4 : 80;
        bf16x8 nbh[4];
#pragma unroll
        for (int nt = 0; nt < 4; nt++)
          nbh[nt] = *(const bf16x8*)&whi[wb0 + (long)t0n * 65536 + nt * 128];
        const int tap = kst * 4 + q;
        const int i = tap / 9, j = tap - i * 9;
        const int aoff = (j & 1) * 6400 + i * 80 + (j >> 1) * 8;
#pragma unroll
        for (int mt = 0; mt < 9; mt++) {
          bf16x8 a = *(const bf16x8*)&slabA[aoff + combo[mt]];
#pragma unroll
          for (int nt = 0; nt < 4; nt++)
            acc[mt][nt] = __builtin_amdgcn_mfma_f32_16x16x32_bf16(a, cbh[nt], acc[mt][nt], 0, 0, 0);
        }
#pragma unroll
        for (int nt = 0; nt < 4; nt++) cbh[nt] = nbh[nt];
      }
    }
  }

  // epilogue: C/D layout col(n)=lane&15, row(m)=q*4+r; atomic over 8 ic-splits
#pragma unroll
  for (int mt = 0; mt < 9; mt++)
#pragma unroll
    for (int nt = 0; nt < 4; nt++) {
      int oc = wv * 64 + nt * 16 + ln16;
      int rowb = mb * 144 + mt * 16 + q * 4;
#pragma unroll
      for (int r = 0; r < 4; r++)
        atomicAdd(&y2[(long)(rowb + r) * 256 + oc], acc[mt][nt][r]);
    }
}

// ================= primary caps squash + predictions + routing ==============
// grid 8192 = g*256 + b; block 256.  y2 layout: [b][pos(36)][c(256)], pre-bias.
__global__ __launch_bounds__(256) void caps_k(
    const float* __restrict__ y2, const float* __restrict__ b2,
    const float* __restrict__ Wcaps, const float* __restrict__ b_route,
    float* __restrict__ vpart) {
  __shared__ float u[288];
  __shared__ float usc[36];
  __shared__ float up[5760];
  __shared__ float bl[360];
  __shared__ float cl[360];
  __shared__ float sv[160];
  __shared__ float vv[160];
  __shared__ float scale[10];
  const int blk = blockIdx.x;
  const int g = blk >> 8, b = blk & 255;
  const int t = threadIdx.x;

  for (int idx = t; idx < 288; idx += 256) {
    int s = idx >> 3, d = idx & 7;
    u[idx] = y2[((long)b * 36 + s) * 256 + g * 8 + d] + b2[g * 8 + d];
  }
  for (int idx = t; idx < 360; idx += 256) bl[idx] = b_route[g * 360 + idx];
  __syncthreads();
  if (t < 36) {
    float l2 = 0.f;
#pragma unroll
    for (int d = 0; d < 8; d++) { float v = u[t * 8 + d]; l2 = fmaf(v, v, l2); }
    float l = sqrtf(l2);
    usc[t] = (l2 / (1.f + l2)) / (l + 1e-8f);
  }
  __syncthreads();
  for (int idx = t; idx < 288; idx += 256) u[idx] *= usc[idx >> 3];
  __syncthreads();
  for (int idx = t; idx < 5760; idx += 256) {
    int s = idx / 160, k = idx - s * 160;
    const float* wp = Wcaps + (g * 36 + s) * 8 * 160 + k;
    float a = 0.f;
#pragma unroll
    for (int d = 0; d < 8; d++) a = fmaf(u[s * 8 + d], wp[d * 160], a);
    up[idx] = a;
  }
  __syncthreads();

  for (int r = 0; r < 3; r++) {
    if (t < 36) {
      float m = bl[t * 10];
#pragma unroll
      for (int oc = 1; oc < 10; oc++) m = fmaxf(m, bl[t * 10 + oc]);
      float e[10]; float sum = 0.f;
#pragma unroll
      for (int oc = 0; oc < 10; oc++) { e[oc] = expf(bl[t * 10 + oc] - m); sum += e[oc]; }
      float inv = 1.f / sum;
#pragma unroll
      for (int oc = 0; oc < 10; oc++) cl[t * 10 + oc] = e[oc] * inv;
    }
    __syncthreads();
    if (t < 160) {
      const int oc = t >> 4;
      float a = 0.f;
#pragma unroll 1
      for (int s = 0; s < 36; s++) a = fmaf(cl[s * 10 + oc], up[s * 160 + t], a);
      sv[t] = a;
    }
    __syncthreads();
    if (t < 10) {
      float l2 = 0.f;
#pragma unroll
      for (int od = 0; od < 16; od++) { float v = sv[t * 16 + od]; l2 = fmaf(v, v, l2); }
      scale[t] = (l2 / (1.f + l2)) / (sqrtf(l2) + 1e-8f);
    }
    __syncthreads();
    if (t < 160) vv[t] = sv[t] * scale[t >> 4];
    __syncthreads();
    if (r < 2) {
      for (int idx = t; idx < 360; idx += 256) {
        int s = idx / 10, oc = idx - s * 10;
        float a = 0.f;
#pragma unroll
        for (int od = 0; od < 16; od++)
          a = fmaf(up[s * 160 + oc * 16 + od], vv[oc * 16 + od], a);
        bl[idx] += a;
      }
      __syncthreads();
    }
  }
  if (t < 160) vpart[(b * 32 + g) * 160 + t] = vv[t];
}

// ================== final: sum over groups + probs ==========================
__global__ __launch_bounds__(192) void final_k(
    const float* __restrict__ vpart, float* __restrict__ out) {
  __shared__ float v[160];
  const int b = blockIdx.x, t = threadIdx.x;
  if (t < 160) {
    float a = 0.f;
#pragma unroll 1
    for (int g = 0; g < 32; g++) a += vpart[(b * 32 + g) * 160 + t];
    v[t] = a;
    out[b * 160 + t] = a;
  }
  __syncthreads();
  if (t < 10) {
    float l2 = 0.f;
#pragma unroll
    for (int od = 0; od < 16; od++) { float x = v[t * 16 + od]; l2 = fmaf(x, x, l2); }
    out[40960 + b * 10 + t] = sqrtf(l2);
  }
}

// ===========================================================================
extern "C" void kernel_launch(void* const* d_in, const int* in_sizes, int n_in,
                              void* d_out, int out_size, void* d_ws, size_t ws_size,
                              hipStream_t stream) {
  const float* inp     = (const float*)d_in[0];
  const float* W1      = (const float*)d_in[1];
  const float* b1      = (const float*)d_in[2];
  const float* W2      = (const float*)d_in[3];
  const float* b2      = (const float*)d_in[4];
  const float* Wcaps   = (const float*)d_in[5];
  const float* b_route = (const float*)d_in[6];
  float* out = (float*)d_out;
  char* ws = (char*)d_ws;

  short* xhi = (short*)(ws + XHI_OFF);
  short* xlo = (short*)(ws + XLO_OFF);
  short* whi = (short*)(ws + WHI_OFF);
  short* wlo = (short*)(ws + WLO_OFF);
  float* y2  = (float*)(ws + Y2_OFF);
  float* vp  = (float*)(ws + VP_OFF);

  hipMemsetAsync(y2, 0, Y2_BYTES, stream);
  conv1_k <<<2048, 320, 0, stream>>>(inp, W1, b1, xhi, xlo);
  wtrans_k<<<21504, 256, 0, stream>>>(W2, whi, wlo);
  conv2_k <<<512, 256, 0, stream>>>(xhi, xlo, whi, wlo, y2);
  caps_k  <<<8192, 256, 0, stream>>>(y2, b2, Wcaps, b_route, vp);
  final_k <<<256, 192, 0, stream>>>(vp, out);
}